// Round 1
// baseline (134.343 us; speedup 1.0000x reference)
//
#include <hip/hip_runtime.h>
#include <math.h>

#define BATCH 32
#define H 512
#define W 512
#define KW 31
#define PAD 15
#define TILE_ROWS 16
#define HS_ROWS (TILE_ROWS + KW - 1)   /* 46 */
#define LDSW 528                       /* swizzled row stride (floats) */
#define NTHREADS 512
#define TILES_PER_IMG (H / TILE_ROWS)  /* 32 */
#define NBLOCKS (BATCH * TILES_PER_IMG) /* 1024 */

__device__ __forceinline__ int swz(int x) { return x + (x >> 5); }

__global__ __launch_bounds__(NTHREADS, 1)
void wbce_pool_kernel(const float* __restrict__ logits,
                      const float* __restrict__ targets,
                      float* __restrict__ partials) {
    __shared__ float hs[HS_ROWS * LDSW];   // 46*528*4 = 97152 B
    __shared__ float raw[8 * LDSW];        // 16896 B
    __shared__ float rn[8], rd[8];

    const int blk  = blockIdx.x;
    const int b    = blk / TILES_PER_IMG;
    const int tile = blk % TILES_PER_IMG;
    const int y0   = tile * TILE_ROWS;
    const int tid  = threadIdx.x;

    const float* tb = targets + (size_t)b * H * W;
    const float* lb = logits  + (size_t)b * H * W;

    // ---- Stage 1: horizontal 31-window sums into hs, in chunks of 8 rows ----
    for (int c0 = 0; c0 < HS_ROWS; c0 += 8) {
        const int nrows = min(8, HS_ROWS - c0);
        // coalesced load of raw target rows (zero outside image)
        for (int i = tid; i < nrows * W; i += NTHREADS) {
            int r = i >> 9;          // i / 512
            int x = i & (W - 1);     // i % 512
            int gy = y0 - PAD + c0 + r;
            float v = (gy >= 0 && gy < H) ? tb[gy * W + x] : 0.f;
            raw[r * LDSW + swz(x)] = v;
        }
        __syncthreads();
        // sliding-window horizontal sums: one task = (row, 32-px segment)
        for (int task = tid; task < nrows * 16; task += NTHREADS) {
            int r = task >> 4;
            int s = task & 15;
            int base = s * 32;
            const float* rw = &raw[r * LDSW];
            float win = 0.f;
            #pragma unroll
            for (int d = -PAD; d <= PAD; ++d) {
                int x = base + d;
                if (x >= 0 && x < W) win += rw[swz(x)];
            }
            float* hrow = &hs[(c0 + r) * LDSW];
            hrow[swz(base)] = win;
            #pragma unroll
            for (int k = 1; k < 32; ++k) {
                int xa = base + k + PAD;      // entering element
                int xs = base + k - PAD - 1;  // leaving element
                float va = (xa < W)  ? rw[swz(xa)] : 0.f;
                float vs = (xs >= 0) ? rw[swz(xs)] : 0.f;
                win += va - vs;
                hrow[swz(base + k)] = win;
            }
        }
        __syncthreads();
    }

    // ---- Stage 2: vertical sliding sum + fused weight/BCE ----
    const int x = tid;  // thread owns one column
    float num = 0.f, den = 0.f;
    float vsum = 0.f;
    #pragma unroll
    for (int r = 0; r < KW; ++r) vsum += hs[r * LDSW + swz(x)];

    #pragma unroll
    for (int j = 0; j < TILE_ROWS; ++j) {
        int y = y0 + j;
        float pooled = vsum * (1.f / (KW * KW));
        float t = tb[y * W + x];
        float l = lb[y * W + x];
        float w = 1.f + 5.f * fabsf(pooled - t);
        float bce = fmaxf(l, 0.f) - l * t + log1pf(expf(-fabsf(l)));
        num += w * bce;
        den += w;
        if (j + 1 < TILE_ROWS) {
            vsum += hs[(j + KW) * LDSW + swz(x)] - hs[j * LDSW + swz(x)];
        }
    }

    // ---- Deterministic block reduction ----
    #pragma unroll
    for (int off = 32; off > 0; off >>= 1) {
        num += __shfl_down(num, off);
        den += __shfl_down(den, off);
    }
    int wid  = tid >> 6;
    int lane = tid & 63;
    if (lane == 0) { rn[wid] = num; rd[wid] = den; }
    __syncthreads();
    if (tid == 0) {
        float n = 0.f, d = 0.f;
        #pragma unroll
        for (int i = 0; i < 8; ++i) { n += rn[i]; d += rd[i]; }
        partials[blk * 2]     = n;
        partials[blk * 2 + 1] = d;
    }
}

// 1024 partial pairs -> scalar; image b owns partial indices [b*32, b*32+32)
__global__ __launch_bounds__(1024)
void wbce_finalize_kernel(const float* __restrict__ partials,
                          float* __restrict__ out) {
    __shared__ float rsum[16];
    int tid = threadIdx.x;
    float num = partials[tid * 2];
    float den = partials[tid * 2 + 1];
    // reduce within each 32-lane group (one image per group)
    #pragma unroll
    for (int off = 16; off > 0; off >>= 1) {
        num += __shfl_down(num, off, 32);
        den += __shfl_down(den, off, 32);
    }
    int lane = tid & 63;
    float ratio = 0.f;
    if ((lane & 31) == 0) ratio = num / den;
    ratio += __shfl_down(ratio, 32);   // lane0 += lane32
    int wid = tid >> 6;
    if (lane == 0) rsum[wid] = ratio;
    __syncthreads();
    if (tid == 0) {
        float s = 0.f;
        #pragma unroll
        for (int i = 0; i < 16; ++i) s += rsum[i];
        out[0] = s / (float)BATCH;
    }
}

extern "C" void kernel_launch(void* const* d_in, const int* in_sizes, int n_in,
                              void* d_out, int out_size, void* d_ws, size_t ws_size,
                              hipStream_t stream) {
    const float* logits  = (const float*)d_in[0];
    const float* targets = (const float*)d_in[1];
    float* out = (float*)d_out;
    float* partials = (float*)d_ws;   // NBLOCKS*2 floats = 8 KB

    wbce_pool_kernel<<<NBLOCKS, NTHREADS, 0, stream>>>(logits, targets, partials);
    wbce_finalize_kernel<<<1, 1024, 0, stream>>>(partials, out);
}

// Round 2
// 48.968 us; speedup vs baseline: 2.7435x; 2.7435x over previous
//
#include <hip/hip_runtime.h>
#include <math.h>

#define BATCH 32
#define H 512
#define W 512
#define PAD 15
#define R 8                        /* output rows per wave */
#define BANDS (H / R)              /* 64 */
#define NWAVES (BATCH * BANDS)     /* 2048 */
#define WPB 4                      /* waves per block */
#define NBLOCKS (NWAVES / WPB)     /* 512 */
#define INV_KK (1.0f / 961.0f)

__global__ __launch_bounds__(WPB * 64)
void wbce_wave_kernel(const float* __restrict__ logits,
                      const float* __restrict__ targets,
                      float* __restrict__ partials) {
    const int tid  = threadIdx.x;
    const int lane = tid & 63;
    const int wid  = blockIdx.x * WPB + (tid >> 6);
    const int img  = wid >> 6;          /* wid / BANDS */
    const int band = wid & (BANDS - 1);
    const int y0   = band * R;
    const int x0   = lane * 8;

    const float* tb = targets + (size_t)img * H * W;
    const float* lb = logits  + (size_t)img * H * W;

    float vsum[8];
    #pragma unroll
    for (int k = 0; k < 8; ++k) vsum[k] = 0.f;

    /* prologue: accumulate rows y0-15 .. y0+15 (zero outside image) */
    for (int y = y0 - PAD; y <= y0 + PAD; ++y) {
        if (y >= 0 && y < H) {
            const float4* rp = (const float4*)(tb + (size_t)y * W + x0);
            float4 a = rp[0], b = rp[1];
            vsum[0] += a.x; vsum[1] += a.y; vsum[2] += a.z; vsum[3] += a.w;
            vsum[4] += b.x; vsum[5] += b.y; vsum[6] += b.z; vsum[7] += b.w;
        }
    }

    float num = 0.f, den = 0.f;

    #pragma unroll
    for (int j = 0; j < R; ++j) {
        const int y = y0 + j;

        /* ---- in-wave prefix scan of the vertical-sum row ---- */
        float p[8];
        p[0] = vsum[0];
        #pragma unroll
        for (int k = 1; k < 8; ++k) p[k] = p[k - 1] + vsum[k];
        float s = p[7];
        #pragma unroll
        for (int off = 1; off < 64; off <<= 1) {
            float t = __shfl_up(s, off);
            if (lane >= off) s += t;
        }
        const float excl = s - p[7];
        float Q[8];
        #pragma unroll
        for (int k = 0; k < 8; ++k) Q[k] = p[k] + excl;
        const float Qtot = __shfl(Q[7], 63);

        /* Qp = Q(x+15) clamped to total; Qm = Q(x-16) or 0 */
        float Qp[8], Qm[8];
        Qp[0] = __shfl_down(Q[7], 1);
        #pragma unroll
        for (int k = 1; k < 8; ++k) Qp[k] = __shfl_down(Q[k - 1], 2);
        #pragma unroll
        for (int k = 0; k < 8; ++k) {
            if (x0 + k + PAD > W - 1) Qp[k] = Qtot;
            float qm = __shfl_up(Q[k], 2);
            Qm[k] = (lane >= 2) ? qm : 0.f;
        }

        /* ---- fused weight + stable BCE ---- */
        const float4* tp = (const float4*)(tb + (size_t)y * W + x0);
        const float4* lp = (const float4*)(lb + (size_t)y * W + x0);
        float4 t0 = tp[0], t1 = tp[1];
        float4 l0 = lp[0], l1 = lp[1];
        float tv[8] = {t0.x, t0.y, t0.z, t0.w, t1.x, t1.y, t1.z, t1.w};
        float lv[8] = {l0.x, l0.y, l0.z, l0.w, l1.x, l1.y, l1.z, l1.w};
        #pragma unroll
        for (int k = 0; k < 8; ++k) {
            float pooled = (Qp[k] - Qm[k]) * INV_KK;
            float w = fmaf(5.f, fabsf(pooled - tv[k]), 1.f);
            float a = fabsf(lv[k]);
            float bce = fmaxf(lv[k], 0.f) - lv[k] * tv[k]
                        + __logf(1.f + __expf(-a));
            num = fmaf(w, bce, num);
            den += w;
        }

        /* ---- slide the vertical window ---- */
        if (j < R - 1) {
            const int ya = y + PAD + 1;
            const int ys = y - PAD;
            float av[8] = {0, 0, 0, 0, 0, 0, 0, 0};
            float sv[8] = {0, 0, 0, 0, 0, 0, 0, 0};
            if (ya < H) {
                const float4* rp = (const float4*)(tb + (size_t)ya * W + x0);
                float4 a = rp[0], b = rp[1];
                av[0] = a.x; av[1] = a.y; av[2] = a.z; av[3] = a.w;
                av[4] = b.x; av[5] = b.y; av[6] = b.z; av[7] = b.w;
            }
            if (ys >= 0) {
                const float4* rp = (const float4*)(tb + (size_t)ys * W + x0);
                float4 a = rp[0], b = rp[1];
                sv[0] = a.x; sv[1] = a.y; sv[2] = a.z; sv[3] = a.w;
                sv[4] = b.x; sv[5] = b.y; sv[6] = b.z; sv[7] = b.w;
            }
            #pragma unroll
            for (int k = 0; k < 8; ++k) vsum[k] += av[k] - sv[k];
        }
    }

    /* ---- wave reduction, one partial pair per wave ---- */
    #pragma unroll
    for (int off = 32; off > 0; off >>= 1) {
        num += __shfl_down(num, off);
        den += __shfl_down(den, off);
    }
    if (lane == 0) {
        partials[wid * 2]     = num;
        partials[wid * 2 + 1] = den;
    }
}

/* 2048 partial pairs -> scalar. Image i owns pairs [i*64, i*64+64). */
__global__ __launch_bounds__(1024)
void wbce_finalize_kernel(const float* __restrict__ partials,
                          float* __restrict__ out) {
    __shared__ float rsum[16];
    const int t = threadIdx.x;
    const int img = t >> 5;
    const int j = t & 31;
    const int base = img * BANDS;
    float num = partials[(base + j) * 2]      + partials[(base + 32 + j) * 2];
    float den = partials[(base + j) * 2 + 1]  + partials[(base + 32 + j) * 2 + 1];
    #pragma unroll
    for (int off = 16; off > 0; off >>= 1) {
        num += __shfl_down(num, off, 32);
        den += __shfl_down(den, off, 32);
    }
    float ratio = 0.f;
    if ((t & 31) == 0) ratio = num / den;
    ratio += __shfl_down(ratio, 32);          /* lane0 += lane32 */
    const int lane = t & 63;
    const int wid = t >> 6;
    if (lane == 0) rsum[wid] = ratio;
    __syncthreads();
    if (t == 0) {
        float s = 0.f;
        #pragma unroll
        for (int i = 0; i < 16; ++i) s += rsum[i];
        out[0] = s / (float)BATCH;
    }
}

extern "C" void kernel_launch(void* const* d_in, const int* in_sizes, int n_in,
                              void* d_out, int out_size, void* d_ws, size_t ws_size,
                              hipStream_t stream) {
    const float* logits  = (const float*)d_in[0];
    const float* targets = (const float*)d_in[1];
    float* out = (float*)d_out;
    float* partials = (float*)d_ws;   /* NWAVES*2 floats = 16 KB */

    wbce_wave_kernel<<<NBLOCKS, WPB * 64, 0, stream>>>(logits, targets, partials);
    wbce_finalize_kernel<<<1, 1024, 0, stream>>>(partials, out);
}